// Round 3
// baseline (345.095 us; speedup 1.0000x reference)
//
#include <hip/hip_runtime.h>
#include <hip/hip_bf16.h>
#include <cstdint>
#include <cstddef>

// Problem constants (B=4, S=4096, D=1024, DFF=4096, K_ACT=1024)
#define Bz 4
#define Sz 4096
#define Dz 1024
#define DFFz 4096
#define KACT 1024

typedef __bf16 bf16;
typedef __attribute__((ext_vector_type(8))) __bf16 bf16x8;
typedef __attribute__((ext_vector_type(4))) __bf16 bf16x4;
typedef __attribute__((ext_vector_type(4))) float f32x4;

__device__ __forceinline__ void async16(const void* g, void* l) {
  __builtin_amdgcn_global_load_lds(
      (const __attribute__((address_space(1))) void*)g,
      (__attribute__((address_space(3))) void*)l, 16, 0, 0);
}

// ---- fused prep: [0,4096) router+zero | [4096,8192) w1 transpose | [8192,12288) w2 transpose ----
__global__ __launch_bounds__(256) void prep_k(const float* __restrict__ x,
                                              const float* __restrict__ rw,
                                              const float* __restrict__ rb,
                                              float* __restrict__ scores,
                                              float4* __restrict__ out4,
                                              const float* __restrict__ w1,
                                              bf16* __restrict__ w1T,
                                              const float* __restrict__ w2,
                                              bf16* __restrict__ w2T) {
  __shared__ float t[32][33];
  const int bid = blockIdx.x;
  const int tid = threadIdx.x;
  if (bid < 4096) {
    int row = bid * 4 + (tid >> 6);
    int lane = tid & 63;
    const float4* xr = (const float4*)(x + (size_t)row * Dz);
    const float4* wr = (const float4*)rw;
    float acc = 0.f;
#pragma unroll
    for (int i = 0; i < 4; ++i) {
      float4 a = xr[lane + i * 64];
      float4 w = wr[lane + i * 64];
      acc += a.x * w.x + a.y * w.y + a.z * w.z + a.w * w.w;
    }
#pragma unroll
    for (int d = 32; d; d >>= 1) acc += __shfl_down(acc, d, 64);
    if (lane == 0) scores[row] = acc + rb[0];
    float4* o = out4 + (size_t)bid * 4 * (Dz / 4);
    const float4 z = make_float4(0.f, 0.f, 0.f, 0.f);
#pragma unroll
    for (int i = 0; i < 4; ++i) o[tid + i * 256] = z;
  } else {
    const float* in; bf16* outp; int R, C, bx, by;
    if (bid < 8192) {
      in = w1; outp = w1T; R = Dz; C = DFFz;
      bx = (bid - 4096) & 127; by = (bid - 4096) >> 7;   // (128, 32)
    } else {
      in = w2; outp = w2T; R = DFFz; C = Dz;
      bx = (bid - 8192) & 31; by = (bid - 8192) >> 5;    // (32, 128)
    }
    int c0 = bx * 32, r0 = by * 32;
    int tx = tid & 31, ty = tid >> 5;  // (32, 8)
#pragma unroll
    for (int i = 0; i < 32; i += 8) t[ty + i][tx] = in[(size_t)(r0 + ty + i) * C + c0 + tx];
    __syncthreads();
#pragma unroll
    for (int i = 0; i < 32; i += 8)
      outp[(size_t)(c0 + ty + i) * R + r0 + tx] = (bf16)t[tx][ty + i];
  }
}

// ---- select top-K per batch, 16 tokens/block: scores staged in LDS once ----
__global__ __launch_bounds__(256) void select_gather_k(
    const float* __restrict__ x, const float* __restrict__ scores,
    int* __restrict__ sel_idx, float* __restrict__ gates, bf16* __restrict__ Xsel) {
  int b = blockIdx.x >> 8;            // 256 blocks per batch row
  int s0 = (blockIdx.x & 255) * 16;   // first of 16 tokens
  __shared__ float sc[Sz];
  __shared__ int red[16][4];
  __shared__ int rk[16];
  const int tid = threadIdx.x;
  const int wave = tid >> 6, lane = tid & 63;
  const float* srow = scores + (size_t)b * Sz;
#pragma unroll
  for (int i = 0; i < 4; ++i)
    ((float4*)sc)[tid + i * 256] = ((const float4*)srow)[tid + i * 256];
  __syncthreads();
  float mine[16];
#pragma unroll
  for (int j = 0; j < 16; ++j) mine[j] = sc[s0 + j];
  int cnt[16] = {};
  for (int t = tid; t < Sz; t += 256) {
    float o = sc[t];
#pragma unroll
    for (int j = 0; j < 16; ++j)
      cnt[j] += (o > mine[j]) || (o == mine[j] && t < s0 + j);
  }
#pragma unroll
  for (int j = 0; j < 16; ++j) {
    int c = cnt[j];
#pragma unroll
    for (int d = 32; d; d >>= 1) c += __shfl_down(c, d, 64);
    if (lane == 0) red[j][wave] = c;
  }
  __syncthreads();
  if (tid < 16) {
    int rank = red[tid][0] + red[tid][1] + red[tid][2] + red[tid][3];
    rk[tid] = rank;
    if (rank < KACT) {
      int m = b * KACT + rank;
      sel_idx[m] = s0 + tid;
      gates[m] = 1.f / (1.f + expf(-sc[s0 + tid]));
    }
  }
  __syncthreads();
#pragma unroll
  for (int j = 0; j < 16; ++j) {
    int rank = rk[j];
    if (rank >= KACT) continue;
    int m = b * KACT + rank;
    float4 v = ((const float4*)(x + ((size_t)b * Sz + s0 + j) * Dz))[tid];
    bf16x4 o = {(bf16)v.x, (bf16)v.y, (bf16)v.z, (bf16)v.w};
    ((bf16x4*)(Xsel + (size_t)m * Dz))[tid] = o;
  }
}

// ======== 3-stage counted-vmcnt GEMM pipeline (T3+T4) ========
// iter t: computes LDS stage t%3; issues global_load_lds for tile t+2 into
// stage (t+2)%3; end-of-iter barrier is raw `s_waitcnt vmcnt(4) lgkmcnt(0);
// s_barrier` -- waits only the OLDEST 4 loads (tile t+1), leaving tile t+2's
// 4 loads in flight across the barrier (never vmcnt(0) in steady state).
// Invariants: buf[t%3] overwritten only at iter t+1 (after a barrier whose
// lgkmcnt(0) drained iter t's ds_reads); buf[t] landed because the barrier
// ending iter t-1 waited the then-oldest-4 = tile t's loads.
// LDS bank swizzle (both-sides-or-neither, rule #21): 64B rows, involution
//   phys = byte ^ (((byte>>7)&3)<<4)
// -> 16-lane column reads spread 2 lanes/bank (free) instead of 8/bank.
// Applied as: linear LDS dest + pre-swizzled GLOBAL source + swizzled ds_read.

#define BAR_VM4 asm volatile("s_waitcnt vmcnt(4) lgkmcnt(0)\n\ts_barrier" ::: "memory")
#define BAR_VM0 asm volatile("s_waitcnt vmcnt(0) lgkmcnt(0)\n\ts_barrier" ::: "memory")

// ---------------- GEMM1: H = gelu(Xsel @ w1 + b1), M=4096 N=4096 K=1024 ----
// 256x256 tile, BK=32, 512 thr / 8 waves (2M x 4N), per-wave 128x64 out.
// grid 16x16 = 256 blocks = 1/CU. LDS 3*(16K+16K) = 96 KB.
__global__ __launch_bounds__(512, 2) void gemm1_k(const bf16* __restrict__ A,
                                                  const bf16* __restrict__ Bt,
                                                  const float* __restrict__ bias,
                                                  bf16* __restrict__ H) {
  __shared__ __align__(16) bf16 SA[3][8192];  // [stage][256 rows][32 k]
  __shared__ __align__(16) bf16 SB[3][8192];
  constexpr int K = Dz;
  constexpr int NITER = K / 32;  // 32
  const int tid = threadIdx.x;
  const int wave = tid >> 6, lane = tid & 63;
  const int quad = lane >> 4, l16 = lane & 15;
  // chunked bijective XCD swizzle (256 % 8 == 0)
  const int orig = blockIdx.y * 16 + blockIdx.x;
  const int wgid = (orig & 7) * 32 + (orig >> 3);
  const int m0 = (wgid >> 4) * 256, n0 = (wgid & 15) * 256;
  const int wm = (wave >> 2) * 128, wn = (wave & 3) * 64;
  // staging: thread handles bytes {tid*16, 8192+tid*16} of each 16 KB tile
  const int Ld0 = tid * 16, Ld1 = 8192 + tid * 16;
  const int q0 = Ld0 ^ (((Ld0 >> 7) & 3) << 4);   // pre-swizzled logical byte
  const int q1 = Ld1 ^ (((Ld1 >> 7) & 3) << 4);
  const char* pa0 = (const char*)A + ((size_t)(m0 + (q0 >> 6)) * K) * 2 + (q0 & 63);
  const char* pa1 = (const char*)A + ((size_t)(m0 + (q1 >> 6)) * K) * 2 + (q1 & 63);
  const char* pb0 = (const char*)Bt + ((size_t)(n0 + (q0 >> 6)) * K) * 2 + (q0 & 63);
  const char* pb1 = (const char*)Bt + ((size_t)(n0 + (q1 >> 6)) * K) * 2 + (q1 & 63);
  // ds_read physical byte offsets (swizzled)
  int aoff[8], boff[4];
#pragma unroll
  for (int i = 0; i < 8; ++i) {
    int r = wm + i * 16 + l16;
    int off = r * 64 + quad * 16;
    aoff[i] = off ^ (((r >> 1) & 3) << 4);
  }
#pragma unroll
  for (int i = 0; i < 4; ++i) {
    int r = wn + i * 16 + l16;
    int off = r * 64 + quad * 16;
    boff[i] = off ^ (((r >> 1) & 3) << 4);
  }
#define STAGE1(sel, t)                                                      \
  {                                                                         \
    char* dA = (char*)&SA[sel][0];                                          \
    char* dB = (char*)&SB[sel][0];                                          \
    size_t ko = (size_t)(t) * 64;                                           \
    async16(pa0 + ko, dA + Ld0);                                            \
    async16(pa1 + ko, dA + Ld1);                                            \
    async16(pb0 + ko, dB + Ld0);                                            \
    async16(pb1 + ko, dB + Ld1);                                            \
  }
  f32x4 acc[8][4] = {};
  STAGE1(0, 0)
  STAGE1(1, 1)
  BAR_VM4;  // tile 0 landed (oldest 4), tile 1 in flight
  for (int t = 0; t < NITER; ++t) {
    const int sel = t % 3;
    const bool more = (t + 2 < NITER);
    if (more) { const int s2 = (t + 2) % 3; STAGE1(s2, t + 2) }
    const char* a = (const char*)&SA[sel][0];
    const char* b = (const char*)&SB[sel][0];
    bf16x8 af[8], bfr[4];
#pragma unroll
    for (int i = 0; i < 8; ++i) af[i] = *(const bf16x8*)(a + aoff[i]);
#pragma unroll
    for (int i = 0; i < 4; ++i) bfr[i] = *(const bf16x8*)(b + boff[i]);
    __builtin_amdgcn_s_setprio(1);
#pragma unroll
    for (int mi = 0; mi < 8; ++mi)
#pragma unroll
      for (int ni = 0; ni < 4; ++ni)
        acc[mi][ni] = __builtin_amdgcn_mfma_f32_16x16x32_bf16(af[mi], bfr[ni], acc[mi][ni], 0, 0, 0);
    __builtin_amdgcn_s_setprio(0);
    if (more) { BAR_VM4; }                       // tile t+1 landed, t+2 in flight
    else if (t + 2 == NITER) { BAR_VM0; }        // drain: tile t+1 landed
    // t == NITER-1: no barrier needed (nothing outstanding, LDS done)
  }
#undef STAGE1
  // epilogue: bias + exact GELU -> bf16  (C/D: col=lane&15, row=quad*4+reg)
#pragma unroll
  for (int mi = 0; mi < 8; ++mi) {
    int mb = m0 + wm + mi * 16 + quad * 4;
#pragma unroll
    for (int ni = 0; ni < 4; ++ni) {
      int n = n0 + wn + ni * 16 + l16;
      float bn = bias[n];
#pragma unroll
      for (int r = 0; r < 4; ++r) {
        float z = acc[mi][ni][r] + bn;
        float g = 0.5f * z * (1.f + erff(z * 0.70710678118654752f));
        H[(size_t)(mb + r) * DFFz + n] = (bf16)g;
      }
    }
  }
}

// ---- GEMM2: out[b,sel[m],:] = (H @ w2 + b2) * gate, fused scatter ----
// 128x128 tile, BK=32, 256 thr / 4 waves (2M x 2N), per-wave 64x64 out.
// grid 8x32 = 256 blocks = 1/CU (fixes round-2's 512-block/2-per-CU grid).
// LDS 3*(8K+8K) = 48 KB. Full K=4096, no split-K, no reduce pass.
__global__ __launch_bounds__(256) void gemm2_k(const bf16* __restrict__ A,
                                               const bf16* __restrict__ Bt,
                                               const float* __restrict__ b2,
                                               const int* __restrict__ sel_idx,
                                               const float* __restrict__ gates,
                                               float* __restrict__ out) {
  __shared__ __align__(16) bf16 SA[3][4096];  // [stage][128 rows][32 k]
  __shared__ __align__(16) bf16 SB[3][4096];
  constexpr int K = DFFz;
  constexpr int NITER = K / 32;  // 128
  const int tid = threadIdx.x;
  const int wave = tid >> 6, lane = tid & 63;
  const int quad = lane >> 4, l16 = lane & 15;
  // chunked bijective XCD swizzle (256 % 8 == 0); grid (8 N, 32 M)
  const int orig = blockIdx.y * 8 + blockIdx.x;
  const int wgid = (orig & 7) * 32 + (orig >> 3);
  const int m0 = (wgid >> 3) * 128, n0 = (wgid & 7) * 128;
  const int wm = (wave >> 1) * 64, wn = (wave & 1) * 64;
  const int Ld0 = tid * 16, Ld1 = 4096 + tid * 16;
  const int q0 = Ld0 ^ (((Ld0 >> 7) & 3) << 4);
  const int q1 = Ld1 ^ (((Ld1 >> 7) & 3) << 4);
  const char* pa0 = (const char*)A + ((size_t)(m0 + (q0 >> 6)) * K) * 2 + (q0 & 63);
  const char* pa1 = (const char*)A + ((size_t)(m0 + (q1 >> 6)) * K) * 2 + (q1 & 63);
  const char* pb0 = (const char*)Bt + ((size_t)(n0 + (q0 >> 6)) * K) * 2 + (q0 & 63);
  const char* pb1 = (const char*)Bt + ((size_t)(n0 + (q1 >> 6)) * K) * 2 + (q1 & 63);
  int aoff[4], boff[4];
#pragma unroll
  for (int i = 0; i < 4; ++i) {
    int ra = wm + i * 16 + l16;
    int oa = ra * 64 + quad * 16;
    aoff[i] = oa ^ (((ra >> 1) & 3) << 4);
    int rb = wn + i * 16 + l16;
    int ob = rb * 64 + quad * 16;
    boff[i] = ob ^ (((rb >> 1) & 3) << 4);
  }
#define STAGE2(sel, t)                                                      \
  {                                                                         \
    char* dA = (char*)&SA[sel][0];                                          \
    char* dB = (char*)&SB[sel][0];                                          \
    size_t ko = (size_t)(t) * 64;                                           \
    async16(pa0 + ko, dA + Ld0);                                            \
    async16(pa1 + ko, dA + Ld1);                                            \
    async16(pb0 + ko, dB + Ld0);                                            \
    async16(pb1 + ko, dB + Ld1);                                            \
  }
  f32x4 acc[4][4] = {};
  STAGE2(0, 0)
  STAGE2(1, 1)
  BAR_VM4;
  for (int t = 0; t < NITER; ++t) {
    const int sel = t % 3;
    const bool more = (t + 2 < NITER);
    if (more) { const int s2 = (t + 2) % 3; STAGE2(s2, t + 2) }
    const char* a = (const char*)&SA[sel][0];
    const char* b = (const char*)&SB[sel][0];
    bf16x8 af[4], bfr[4];
#pragma unroll
    for (int i = 0; i < 4; ++i) af[i] = *(const bf16x8*)(a + aoff[i]);
#pragma unroll
    for (int i = 0; i < 4; ++i) bfr[i] = *(const bf16x8*)(b + boff[i]);
    __builtin_amdgcn_s_setprio(1);
#pragma unroll
    for (int mi = 0; mi < 4; ++mi)
#pragma unroll
      for (int ni = 0; ni < 4; ++ni)
        acc[mi][ni] = __builtin_amdgcn_mfma_f32_16x16x32_bf16(af[mi], bfr[ni], acc[mi][ni], 0, 0, 0);
    __builtin_amdgcn_s_setprio(0);
    if (more) { BAR_VM4; }
    else if (t + 2 == NITER) { BAR_VM0; }
  }
#undef STAGE2
  // fused epilogue: +b2, gate, scatter to out rows (out pre-zeroed by prep_k)
#pragma unroll
  for (int mi = 0; mi < 4; ++mi) {
#pragma unroll
    for (int r = 0; r < 4; ++r) {
      int m = m0 + wm + mi * 16 + quad * 4 + r;
      int b = m >> 10;
      int s = sel_idx[m];
      float g = gates[m];
      float* orow = out + ((size_t)b * Sz + s) * Dz;
#pragma unroll
      for (int ni = 0; ni < 4; ++ni) {
        int n = n0 + wn + ni * 16 + l16;
        orow[n] = (acc[mi][ni][r] + b2[n]) * g;
      }
    }
  }
}

extern "C" void kernel_launch(void* const* d_in, const int* in_sizes, int n_in,
                              void* d_out, int out_size, void* d_ws, size_t ws_size,
                              hipStream_t stream) {
  (void)in_sizes; (void)n_in; (void)out_size; (void)ws_size;
  const float* x  = (const float*)d_in[0];
  const float* rw = (const float*)d_in[1];
  const float* rb = (const float*)d_in[2];
  const float* w1 = (const float*)d_in[3];
  const float* b1 = (const float*)d_in[4];
  const float* w2 = (const float*)d_in[5];
  const float* b2 = (const float*)d_in[6];
  float* out = (float*)d_out;

  char* ws = (char*)d_ws;
  float* scores = (float*)ws;  ws += (size_t)Bz * Sz * 4;          // 64 KB
  int*   sel_idx = (int*)ws;   ws += (size_t)Bz * KACT * 4;        // 16 KB
  float* gates = (float*)ws;   ws += (size_t)Bz * KACT * 4;        // 16 KB
  bf16*  w2T = (bf16*)ws;      ws += (size_t)Dz * DFFz * 2;        // 8 MB  [1024][4096]
  bf16*  H = (bf16*)ws;        ws += (size_t)Bz * KACT * DFFz * 2; // 32 MB [4096][4096]
  bf16*  w1T = (bf16*)ws;      ws += (size_t)DFFz * Dz * 2;        // 8 MB  [4096][1024]
  bf16*  Xsel = (bf16*)ws;     ws += (size_t)Bz * KACT * Dz * 2;   // 8 MB  [4096][1024]

  prep_k<<<3 * 4096, 256, 0, stream>>>(x, rw, rb, scores, (float4*)out, w1, w1T, w2, w2T);
  select_gather_k<<<Bz * (Sz / 16), 256, 0, stream>>>(x, scores, sel_idx, gates, Xsel);
  gemm1_k<<<dim3(16, 16), 512, 0, stream>>>(Xsel, w1T, b1, H);
  gemm2_k<<<dim3(8, 32), 256, 0, stream>>>(H, w2T, b2, sel_idx, gates, out);
}

// Round 4
// 306.358 us; speedup vs baseline: 1.1264x; 1.1264x over previous
//
#include <hip/hip_runtime.h>
#include <hip/hip_bf16.h>
#include <cstdint>
#include <cstddef>

// Problem constants (B=4, S=4096, D=1024, DFF=4096, K_ACT=1024)
#define Bz 4
#define Sz 4096
#define Dz 1024
#define DFFz 4096
#define KACT 1024

typedef __bf16 bf16;
typedef __attribute__((ext_vector_type(8))) __bf16 bf16x8;
typedef __attribute__((ext_vector_type(4))) __bf16 bf16x4;
typedef __attribute__((ext_vector_type(4))) float f32x4;

__device__ __forceinline__ void async16(const void* g, void* l) {
  __builtin_amdgcn_global_load_lds(
      (const __attribute__((address_space(1))) void*)g,
      (__attribute__((address_space(3))) void*)l, 16, 0, 0);
}

// ---- fused prep: [0,4096) router+zero | [4096,8192) w1 transpose | [8192,12288) w2 transpose ----
__global__ __launch_bounds__(256) void prep_k(const float* __restrict__ x,
                                              const float* __restrict__ rw,
                                              const float* __restrict__ rb,
                                              float* __restrict__ scores,
                                              float4* __restrict__ out4,
                                              const float* __restrict__ w1,
                                              bf16* __restrict__ w1T,
                                              const float* __restrict__ w2,
                                              bf16* __restrict__ w2T) {
  __shared__ float t[32][33];
  const int bid = blockIdx.x;
  const int tid = threadIdx.x;
  if (bid < 4096) {
    int row = bid * 4 + (tid >> 6);
    int lane = tid & 63;
    const float4* xr = (const float4*)(x + (size_t)row * Dz);
    const float4* wr = (const float4*)rw;
    float acc = 0.f;
#pragma unroll
    for (int i = 0; i < 4; ++i) {
      float4 a = xr[lane + i * 64];
      float4 w = wr[lane + i * 64];
      acc += a.x * w.x + a.y * w.y + a.z * w.z + a.w * w.w;
    }
#pragma unroll
    for (int d = 32; d; d >>= 1) acc += __shfl_down(acc, d, 64);
    if (lane == 0) scores[row] = acc + rb[0];
    float4* o = out4 + (size_t)bid * 4 * (Dz / 4);
    const float4 z = make_float4(0.f, 0.f, 0.f, 0.f);
#pragma unroll
    for (int i = 0; i < 4; ++i) o[tid + i * 256] = z;
  } else {
    const float* in; bf16* outp; int R, C, bx, by;
    if (bid < 8192) {
      in = w1; outp = w1T; R = Dz; C = DFFz;
      bx = (bid - 4096) & 127; by = (bid - 4096) >> 7;   // (128, 32)
    } else {
      in = w2; outp = w2T; R = DFFz; C = Dz;
      bx = (bid - 8192) & 31; by = (bid - 8192) >> 5;    // (32, 128)
    }
    int c0 = bx * 32, r0 = by * 32;
    int tx = tid & 31, ty = tid >> 5;  // (32, 8)
#pragma unroll
    for (int i = 0; i < 32; i += 8) t[ty + i][tx] = in[(size_t)(r0 + ty + i) * C + c0 + tx];
    __syncthreads();
#pragma unroll
    for (int i = 0; i < 32; i += 8)
      outp[(size_t)(c0 + ty + i) * R + r0 + tx] = (bf16)t[tx][ty + i];
  }
}

// ---- select top-K per batch, 16 tokens/block: scores staged in LDS once ----
__global__ __launch_bounds__(256) void select_gather_k(
    const float* __restrict__ x, const float* __restrict__ scores,
    int* __restrict__ sel_idx, float* __restrict__ gates, bf16* __restrict__ Xsel) {
  int b = blockIdx.x >> 8;            // 256 blocks per batch row
  int s0 = (blockIdx.x & 255) * 16;   // first of 16 tokens
  __shared__ float sc[Sz];
  __shared__ int red[16][4];
  __shared__ int rk[16];
  const int tid = threadIdx.x;
  const int wave = tid >> 6, lane = tid & 63;
  const float* srow = scores + (size_t)b * Sz;
#pragma unroll
  for (int i = 0; i < 4; ++i)
    ((float4*)sc)[tid + i * 256] = ((const float4*)srow)[tid + i * 256];
  __syncthreads();
  float mine[16];
#pragma unroll
  for (int j = 0; j < 16; ++j) mine[j] = sc[s0 + j];
  int cnt[16] = {};
  for (int t = tid; t < Sz; t += 256) {
    float o = sc[t];
#pragma unroll
    for (int j = 0; j < 16; ++j)
      cnt[j] += (o > mine[j]) || (o == mine[j] && t < s0 + j);
  }
#pragma unroll
  for (int j = 0; j < 16; ++j) {
    int c = cnt[j];
#pragma unroll
    for (int d = 32; d; d >>= 1) c += __shfl_down(c, d, 64);
    if (lane == 0) red[j][wave] = c;
  }
  __syncthreads();
  if (tid < 16) {
    int rank = red[tid][0] + red[tid][1] + red[tid][2] + red[tid][3];
    rk[tid] = rank;
    if (rank < KACT) {
      int m = b * KACT + rank;
      sel_idx[m] = s0 + tid;
      gates[m] = 1.f / (1.f + expf(-sc[s0 + tid]));
    }
  }
  __syncthreads();
#pragma unroll
  for (int j = 0; j < 16; ++j) {
    int rank = rk[j];
    if (rank >= KACT) continue;
    int m = b * KACT + rank;
    float4 v = ((const float4*)(x + ((size_t)b * Sz + s0 + j) * Dz))[tid];
    bf16x4 o = {(bf16)v.x, (bf16)v.y, (bf16)v.z, (bf16)v.w};
    ((bf16x4*)(Xsel + (size_t)m * Dz))[tid] = o;
  }
}

// ======== 3-stage counted-vmcnt GEMM pipeline, DISTINCT LDS arrays ========
// R3 failure mechanism: with one SA[3][...] array and runtime stage index,
// LLVM's SIInsertWaitcnts cannot disambiguate the LDS-DMA (global_load_lds)
// writes from the ds_reads and conservatively inserts s_waitcnt vmcnt(0)
// BEFORE the ds_reads -- right after tile t+2's loads were issued -> full
// latency serially exposed each iteration (9375 cy/iter measured).
// Fix: 3 distinct __shared__ arrays per operand + pipeline unrolled x3 so
// every stage index is compile-time. DMA memoperands then target distinct
// LDS objects; reads of stage s don't alias in-flight DMAs to s+1/s+2, so
// no spurious drain. Cross-wave ordering invariants (explicit asm barrier):
//  - buf s reused by DMA only in body t+3k after the barrier ending body
//    t+2 whose lgkmcnt(0) completed ALL waves' reads of s.
//  - reads of s in body t see tile t's data: barrier ending body t-1 did
//    vmcnt(4) with outstanding {tile t (oldest 4), tile t+1 (4)} -> waits
//    tile t per wave, then s_barrier joins all waves.
// Worst case (alias analysis still conservative): degenerates to R1-level
// per-iter drain, hidden by 3 blocks/CU (48 KB LDS) -- downside bounded.
// LDS bank swizzle kept (R3 proved conflicts 4.2M -> 0): involution
//   phys = byte ^ (((byte>>7)&3)<<4)   (64 B rows)
// applied as linear LDS dest + pre-swizzled GLOBAL source + swizzled ds_read.

#define BAR_VM4 asm volatile("s_waitcnt vmcnt(4) lgkmcnt(0)\n\ts_barrier" ::: "memory")
#define BAR_VM0 asm volatile("s_waitcnt vmcnt(0) lgkmcnt(0)\n\ts_barrier" ::: "memory")

// stage tile T (k-offset T*32 elems = T*64 bytes) into arrays AS/BS (8 KB each)
#define STG(AS, BS, T)                                                        \
  {                                                                           \
    size_t ko = (size_t)(T) * 64;                                             \
    async16(pa0 + ko, (char*)AS + Ld0);                                       \
    async16(pa1 + ko, (char*)AS + Ld1);                                       \
    async16(pb0 + ko, (char*)BS + Ld0);                                       \
    async16(pb1 + ko, (char*)BS + Ld1);                                       \
  }

// one pipeline body: optionally stage tile T+2 into AST/BST, compute from
// ARD/BRD, then barrier (BARK 0: vmcnt(4), 1: vmcnt(0), 2: none)
#define GBODY(ARD, BRD, AST, BST, T, DOSTAGE, BARK)                           \
  {                                                                           \
    if (DOSTAGE) { STG(AST, BST, (T) + 2) }                                   \
    bf16x8 af[4], bfr[4];                                                     \
    const char* a_ = (const char*)ARD;                                        \
    const char* b_ = (const char*)BRD;                                        \
    _Pragma("unroll") for (int i = 0; i < 4; ++i) {                           \
      af[i] = *(const bf16x8*)(a_ + aoff[i]);                                 \
      bfr[i] = *(const bf16x8*)(b_ + boff[i]);                                \
    }                                                                         \
    __builtin_amdgcn_s_setprio(1);                                            \
    _Pragma("unroll") for (int mi = 0; mi < 4; ++mi)                          \
      _Pragma("unroll") for (int ni = 0; ni < 4; ++ni)                        \
        acc[mi][ni] = __builtin_amdgcn_mfma_f32_16x16x32_bf16(                \
            af[mi], bfr[ni], acc[mi][ni], 0, 0, 0);                           \
    __builtin_amdgcn_s_setprio(0);                                            \
    if ((BARK) == 0) { BAR_VM4; }                                             \
    else if ((BARK) == 1) { BAR_VM0; }                                        \
  }

// common per-kernel setup: 128x128 tile, 4 waves (2M x 2N), 64 B LDS rows
#define GSETUP(APTR, BPTR, KV, KOFFB)                                         \
  const int tid = threadIdx.x;                                                \
  const int wave = tid >> 6, lane = tid & 63;                                 \
  const int quad = lane >> 4, l16 = lane & 15;                                \
  const int wm = (wave >> 1) * 64, wn = (wave & 1) * 64;                      \
  const int Ld0 = tid * 16, Ld1 = 4096 + tid * 16;                            \
  const int q0 = Ld0 ^ (((Ld0 >> 7) & 3) << 4);                               \
  const int q1 = Ld1 ^ (((Ld1 >> 7) & 3) << 4);                               \
  const char* pa0 = (const char*)(APTR) +                                     \
      ((size_t)(m0 + (q0 >> 6)) * (KV)) * 2 + (KOFFB) + (q0 & 63);            \
  const char* pa1 = (const char*)(APTR) +                                     \
      ((size_t)(m0 + (q1 >> 6)) * (KV)) * 2 + (KOFFB) + (q1 & 63);            \
  const char* pb0 = (const char*)(BPTR) +                                     \
      ((size_t)(n0 + (q0 >> 6)) * (KV)) * 2 + (KOFFB) + (q0 & 63);            \
  const char* pb1 = (const char*)(BPTR) +                                     \
      ((size_t)(n0 + (q1 >> 6)) * (KV)) * 2 + (KOFFB) + (q1 & 63);            \
  int aoff[4], boff[4];                                                       \
  _Pragma("unroll") for (int i = 0; i < 4; ++i) {                             \
    int ra = wm + i * 16 + l16;                                               \
    int oa = ra * 64 + quad * 16;                                             \
    aoff[i] = oa ^ (((ra >> 1) & 3) << 4);                                    \
    int rb = wn + i * 16 + l16;                                               \
    int ob = rb * 64 + quad * 16;                                             \
    boff[i] = ob ^ (((rb >> 1) & 3) << 4);                                    \
  }                                                                           \
  f32x4 acc[4][4] = {};

// ---------------- GEMM1: H = gelu(Xsel @ w1 + b1), M=4096 N=4096 K=1024 ----
// grid 32x32 = 1024 blocks -> up to 4/CU (LDS 48KB -> 3/CU). NITER = 32.
__global__ __launch_bounds__(256) void gemm1_k(const bf16* __restrict__ A,
                                               const bf16* __restrict__ Bt,
                                               const float* __restrict__ bias,
                                               bf16* __restrict__ H) {
  __shared__ __align__(16) bf16 A0[4096], A1[4096], A2[4096];  // 8 KB each
  __shared__ __align__(16) bf16 B0[4096], B1[4096], B2[4096];
  const int orig = blockIdx.y * 32 + blockIdx.x;               // nwg=1024
  const int wgid = (orig & 7) * 128 + (orig >> 3);             // bijective XCD chunk
  const int m0 = (wgid >> 5) * 128, n0 = (wgid & 31) * 128;
  GSETUP(A, Bt, Dz, 0)
  STG(A0, B0, 0)
  STG(A1, B1, 1)
  BAR_VM4;  // tile 0 landed (oldest 4), tile 1 in flight
  for (int tt = 0; tt < 10; ++tt) {   // bodies t = 0..29
    const int t0 = tt * 3;
    GBODY(A0, B0, A2, B2, t0 + 0, 1, 0)   // stages tile t0+2 -> stage 2
    GBODY(A1, B1, A0, B0, t0 + 1, 1, 0)   // stages tile t0+3 -> stage 0
    GBODY(A2, B2, A1, B1, t0 + 2, 1, 0)   // stages tile t0+4 -> stage 1
  }
  GBODY(A0, B0, A0, B0, 30, 0, 1)   // no stage; vmcnt(0): tile 31 landed
  GBODY(A1, B1, A0, B0, 31, 0, 2)   // no stage; no barrier
  // epilogue: bias + exact GELU -> bf16  (C/D: col=lane&15, row=quad*4+reg)
#pragma unroll
  for (int mi = 0; mi < 4; ++mi) {
    int mb = m0 + wm + mi * 16 + quad * 4;
#pragma unroll
    for (int ni = 0; ni < 4; ++ni) {
      int n = n0 + wn + ni * 16 + l16;
      float bn = bias[n];
#pragma unroll
      for (int r = 0; r < 4; ++r) {
        float z = acc[mi][ni][r] + bn;
        float g = 0.5f * z * (1.f + erff(z * 0.70710678118654752f));
        H[(size_t)(mb + r) * DFFz + n] = (bf16)g;
      }
    }
  }
}

// ---- GEMM2: out[b,sel[m],:] += (H @ w2 [+ b2]) * gate, split-K=2, atomic scatter ----
// M=4096 N=1024 Kchunk=2048 -> NITER=64; grid (8,32,2) = 512 blocks = 2/CU.
// out pre-zeroed by prep_k each launch; f32 atomicAdd is order-independent.
__global__ __launch_bounds__(256) void gemm2_k(const bf16* __restrict__ A,
                                               const bf16* __restrict__ Bt,
                                               const float* __restrict__ b2,
                                               const int* __restrict__ sel_idx,
                                               const float* __restrict__ gates,
                                               float* __restrict__ out) {
  __shared__ __align__(16) bf16 A0[4096], A1[4096], A2[4096];
  __shared__ __align__(16) bf16 B0[4096], B1[4096], B2[4096];
  const int orig = blockIdx.y * 8 + blockIdx.x;                // nwg=256 per z
  const int wgid = (orig & 7) * 32 + (orig >> 3);              // bijective XCD chunk
  const int m0 = (wgid >> 3) * 128, n0 = (wgid & 7) * 128;
  GSETUP(A, Bt, DFFz, (size_t)blockIdx.z * 2048 * 2)
  STG(A0, B0, 0)
  STG(A1, B1, 1)
  BAR_VM4;
  for (int tt = 0; tt < 20; ++tt) {   // bodies t = 0..59
    const int t0 = tt * 3;
    GBODY(A0, B0, A2, B2, t0 + 0, 1, 0)
    GBODY(A1, B1, A0, B0, t0 + 1, 1, 0)
    GBODY(A2, B2, A1, B1, t0 + 2, 1, 0)
  }
  GBODY(A0, B0, A2, B2, 60, 1, 0)   // stages tile 62 -> stage 2
  GBODY(A1, B1, A0, B0, 61, 1, 0)   // stages tile 63 -> stage 0; waits tile 62
  GBODY(A2, B2, A0, B0, 62, 0, 1)   // vmcnt(0): tile 63 landed
  GBODY(A0, B0, A0, B0, 63, 0, 2)   // no barrier
  // fused epilogue: (+b2 on z==0), gate, atomic scatter into zeroed out
  const bool addb = (blockIdx.z == 0);
#pragma unroll
  for (int mi = 0; mi < 4; ++mi) {
#pragma unroll
    for (int r = 0; r < 4; ++r) {
      int m = m0 + wm + mi * 16 + quad * 4 + r;
      int b = m >> 10;
      int s = sel_idx[m];
      float g = gates[m];
      float* orow = out + ((size_t)b * Sz + s) * Dz;
#pragma unroll
      for (int ni = 0; ni < 4; ++ni) {
        int n = n0 + wn + ni * 16 + l16;
        float v = acc[mi][ni][r] + (addb ? b2[n] : 0.f);
        atomicAdd(&orow[n], v * g);
      }
    }
  }
}

extern "C" void kernel_launch(void* const* d_in, const int* in_sizes, int n_in,
                              void* d_out, int out_size, void* d_ws, size_t ws_size,
                              hipStream_t stream) {
  (void)in_sizes; (void)n_in; (void)out_size; (void)ws_size;
  const float* x  = (const float*)d_in[0];
  const float* rw = (const float*)d_in[1];
  const float* rb = (const float*)d_in[2];
  const float* w1 = (const float*)d_in[3];
  const float* b1 = (const float*)d_in[4];
  const float* w2 = (const float*)d_in[5];
  const float* b2 = (const float*)d_in[6];
  float* out = (float*)d_out;

  char* ws = (char*)d_ws;
  float* scores = (float*)ws;  ws += (size_t)Bz * Sz * 4;          // 64 KB
  int*   sel_idx = (int*)ws;   ws += (size_t)Bz * KACT * 4;        // 16 KB
  float* gates = (float*)ws;   ws += (size_t)Bz * KACT * 4;        // 16 KB
  bf16*  w2T = (bf16*)ws;      ws += (size_t)Dz * DFFz * 2;        // 8 MB  [1024][4096]
  bf16*  H = (bf16*)ws;        ws += (size_t)Bz * KACT * DFFz * 2; // 32 MB [4096][4096]
  bf16*  w1T = (bf16*)ws;      ws += (size_t)DFFz * Dz * 2;        // 8 MB  [4096][1024]
  bf16*  Xsel = (bf16*)ws;     ws += (size_t)Bz * KACT * Dz * 2;   // 8 MB  [4096][1024]

  prep_k<<<3 * 4096, 256, 0, stream>>>(x, rw, rb, scores, (float4*)out, w1, w1T, w2, w2T);
  select_gather_k<<<Bz * (Sz / 16), 256, 0, stream>>>(x, scores, sel_idx, gates, Xsel);
  gemm1_k<<<dim3(32, 32), 256, 0, stream>>>(Xsel, w1T, b1, H);
  gemm2_k<<<dim3(8, 32, 2), 256, 0, stream>>>(H, w2T, b2, sel_idx, gates, out);
}

// Round 5
// 304.120 us; speedup vs baseline: 1.1347x; 1.0074x over previous
//
#include <hip/hip_runtime.h>
#include <hip/hip_bf16.h>
#include <cstdint>
#include <cstddef>

// Problem constants (B=4, S=4096, D=1024, DFF=4096, K_ACT=1024)
#define Bz 4
#define Sz 4096
#define Dz 1024
#define DFFz 4096
#define KACT 1024

typedef __bf16 bf16;
typedef __attribute__((ext_vector_type(8))) __bf16 bf16x8;
typedef __attribute__((ext_vector_type(4))) __bf16 bf16x4;
typedef __attribute__((ext_vector_type(4))) float f32x4;

__device__ __forceinline__ void async16(const void* g, void* l) {
  __builtin_amdgcn_global_load_lds(
      (const __attribute__((address_space(1))) void*)g,
      (__attribute__((address_space(3))) void*)l, 16, 0, 0);
}

// ---- fused prep: [0,4096) router+zero | [4096,8192) w1 transpose | [8192,12288) w2 transpose ----
__global__ __launch_bounds__(256) void prep_k(const float* __restrict__ x,
                                              const float* __restrict__ rw,
                                              const float* __restrict__ rb,
                                              float* __restrict__ scores,
                                              float4* __restrict__ out4,
                                              const float* __restrict__ w1,
                                              bf16* __restrict__ w1T,
                                              const float* __restrict__ w2,
                                              bf16* __restrict__ w2T) {
  __shared__ float t[32][33];
  const int bid = blockIdx.x;
  const int tid = threadIdx.x;
  if (bid < 4096) {
    int row = bid * 4 + (tid >> 6);
    int lane = tid & 63;
    const float4* xr = (const float4*)(x + (size_t)row * Dz);
    const float4* wr = (const float4*)rw;
    float acc = 0.f;
#pragma unroll
    for (int i = 0; i < 4; ++i) {
      float4 a = xr[lane + i * 64];
      float4 w = wr[lane + i * 64];
      acc += a.x * w.x + a.y * w.y + a.z * w.z + a.w * w.w;
    }
#pragma unroll
    for (int d = 32; d; d >>= 1) acc += __shfl_down(acc, d, 64);
    if (lane == 0) scores[row] = acc + rb[0];
    float4* o = out4 + (size_t)bid * 4 * (Dz / 4);
    const float4 z = make_float4(0.f, 0.f, 0.f, 0.f);
#pragma unroll
    for (int i = 0; i < 4; ++i) o[tid + i * 256] = z;
  } else {
    const float* in; bf16* outp; int R, C, bx, by;
    if (bid < 8192) {
      in = w1; outp = w1T; R = Dz; C = DFFz;
      bx = (bid - 4096) & 127; by = (bid - 4096) >> 7;   // (128, 32)
    } else {
      in = w2; outp = w2T; R = DFFz; C = Dz;
      bx = (bid - 8192) & 31; by = (bid - 8192) >> 5;    // (32, 128)
    }
    int c0 = bx * 32, r0 = by * 32;
    int tx = tid & 31, ty = tid >> 5;  // (32, 8)
#pragma unroll
    for (int i = 0; i < 32; i += 8) t[ty + i][tx] = in[(size_t)(r0 + ty + i) * C + c0 + tx];
    __syncthreads();
#pragma unroll
    for (int i = 0; i < 32; i += 8)
      outp[(size_t)(c0 + ty + i) * R + r0 + tx] = (bf16)t[tx][ty + i];
  }
}

// ---- select top-K per batch, 16 tokens/block: scores staged in LDS once ----
__global__ __launch_bounds__(256) void select_gather_k(
    const float* __restrict__ x, const float* __restrict__ scores,
    int* __restrict__ sel_idx, float* __restrict__ gates, bf16* __restrict__ Xsel) {
  int b = blockIdx.x >> 8;            // 256 blocks per batch row
  int s0 = (blockIdx.x & 255) * 16;   // first of 16 tokens
  __shared__ float sc[Sz];
  __shared__ int red[16][4];
  __shared__ int rk[16];
  const int tid = threadIdx.x;
  const int wave = tid >> 6, lane = tid & 63;
  const float* srow = scores + (size_t)b * Sz;
#pragma unroll
  for (int i = 0; i < 4; ++i)
    ((float4*)sc)[tid + i * 256] = ((const float4*)srow)[tid + i * 256];
  __syncthreads();
  float mine[16];
#pragma unroll
  for (int j = 0; j < 16; ++j) mine[j] = sc[s0 + j];
  int cnt[16] = {};
  for (int t = tid; t < Sz; t += 256) {
    float o = sc[t];
#pragma unroll
    for (int j = 0; j < 16; ++j)
      cnt[j] += (o > mine[j]) || (o == mine[j] && t < s0 + j);
  }
#pragma unroll
  for (int j = 0; j < 16; ++j) {
    int c = cnt[j];
#pragma unroll
    for (int d = 32; d; d >>= 1) c += __shfl_down(c, d, 64);
    if (lane == 0) red[j][wave] = c;
  }
  __syncthreads();
  if (tid < 16) {
    int rank = red[tid][0] + red[tid][1] + red[tid][2] + red[tid][3];
    rk[tid] = rank;
    if (rank < KACT) {
      int m = b * KACT + rank;
      sel_idx[m] = s0 + tid;
      gates[m] = 1.f / (1.f + expf(-sc[s0 + tid]));
    }
  }
  __syncthreads();
#pragma unroll
  for (int j = 0; j < 16; ++j) {
    int rank = rk[j];
    if (rank >= KACT) continue;
    int m = b * KACT + rank;
    float4 v = ((const float4*)(x + ((size_t)b * Sz + s0 + j) * Dz))[tid];
    bf16x4 o = {(bf16)v.x, (bf16)v.y, (bf16)v.z, (bf16)v.w};
    ((bf16x4*)(Xsel + (size_t)m * Dz))[tid] = o;
  }
}

// ======== 4-stage counted-vmcnt GEMM pipeline (prefetch distance 3) ========
// R4 diagnosis: depth-2 prefetch left ~500-900 cy of DMA latency exposed per
// iteration (1331 cy/iter-slot vs ~256 cy MFMA; HBM-miss latency ~900 cy).
// Depth 4 gives a 3-iteration lead (~1500 cy) > latency -> fully covered.
// Body order: ds_reads FIRST (compiler's alias-wait vmcnt(8) before them is
// already satisfied by the previous barrier), then STG tile t+3, then MFMA,
// then `s_waitcnt vmcnt(8) lgkmcnt(0); s_barrier`.
// Invariants (tile t -> stage t%4, all indices compile-time):
//  - reads of stage t%4 in body t see tile t: barrier ending body t-1 did
//    vmcnt(8) over outstanding {t(oldest 4), t+1, t+2} -> tile t complete
//    in every wave, then s_barrier joins.
//  - STG into stage (t+3)%4 in body t overwrites stage last READ in body
//    t-1; that barrier's lgkmcnt(0)+join drained ALL waves' reads first.
// Tail (no stage): vmcnt(4) -> vmcnt(0) -> no barrier.
// LDS bank swizzle kept byte-identical (R3/R4 measured conflicts = 0):
//   phys = byte ^ (((byte>>7)&3)<<4), linear LDS dest + pre-swizzled global
//   source + swizzled ds_read offsets (both-sides-or-neither).

#define BAR_VM8 asm volatile("s_waitcnt vmcnt(8) lgkmcnt(0)\n\ts_barrier" ::: "memory")
#define BAR_VM4 asm volatile("s_waitcnt vmcnt(4) lgkmcnt(0)\n\ts_barrier" ::: "memory")
#define BAR_VM0 asm volatile("s_waitcnt vmcnt(0) lgkmcnt(0)\n\ts_barrier" ::: "memory")

// stage tile T (k-offset T*32 elems = T*64 bytes) into arrays AS/BS (8 KB each)
#define STG(AS, BS, T)                                                        \
  {                                                                           \
    size_t ko = (size_t)(T) * 64;                                             \
    async16(pa0 + ko, (char*)AS + Ld0);                                       \
    async16(pa1 + ko, (char*)AS + Ld1);                                       \
    async16(pb0 + ko, (char*)BS + Ld0);                                       \
    async16(pb1 + ko, (char*)BS + Ld1);                                       \
  }

// one pipeline body: ds_reads from ARD/BRD, optionally stage tile T+3 into
// AST/BST, MFMA, then barrier (BARK 0: vmcnt(8), 1: vmcnt(4), 2: vmcnt(0), 3: none)
#define GBODY(ARD, BRD, AST, BST, T, DOSTAGE, BARK)                           \
  {                                                                           \
    bf16x8 af[4], bfr[4];                                                     \
    const char* a_ = (const char*)ARD;                                        \
    const char* b_ = (const char*)BRD;                                        \
    _Pragma("unroll") for (int i = 0; i < 4; ++i) {                           \
      af[i] = *(const bf16x8*)(a_ + aoff[i]);                                 \
      bfr[i] = *(const bf16x8*)(b_ + boff[i]);                                \
    }                                                                         \
    if (DOSTAGE) { STG(AST, BST, (T) + 3) }                                   \
    __builtin_amdgcn_s_setprio(1);                                            \
    _Pragma("unroll") for (int mi = 0; mi < 4; ++mi)                          \
      _Pragma("unroll") for (int ni = 0; ni < 4; ++ni)                        \
        acc[mi][ni] = __builtin_amdgcn_mfma_f32_16x16x32_bf16(                \
            af[mi], bfr[ni], acc[mi][ni], 0, 0, 0);                           \
    __builtin_amdgcn_s_setprio(0);                                            \
    if ((BARK) == 0) { BAR_VM8; }                                             \
    else if ((BARK) == 1) { BAR_VM4; }                                        \
    else if ((BARK) == 2) { BAR_VM0; }                                        \
  }

// common per-kernel setup: 128x128 tile, 4 waves (2M x 2N), 64 B LDS rows
#define GSETUP(APTR, BPTR, KV, KOFFB)                                         \
  const int tid = threadIdx.x;                                                \
  const int wave = tid >> 6, lane = tid & 63;                                 \
  const int quad = lane >> 4, l16 = lane & 15;                                \
  const int wm = (wave >> 1) * 64, wn = (wave & 1) * 64;                      \
  const int Ld0 = tid * 16, Ld1 = 4096 + tid * 16;                            \
  const int q0 = Ld0 ^ (((Ld0 >> 7) & 3) << 4);                               \
  const int q1 = Ld1 ^ (((Ld1 >> 7) & 3) << 4);                               \
  const char* pa0 = (const char*)(APTR) +                                     \
      ((size_t)(m0 + (q0 >> 6)) * (KV)) * 2 + (KOFFB) + (q0 & 63);            \
  const char* pa1 = (const char*)(APTR) +                                     \
      ((size_t)(m0 + (q1 >> 6)) * (KV)) * 2 + (KOFFB) + (q1 & 63);            \
  const char* pb0 = (const char*)(BPTR) +                                     \
      ((size_t)(n0 + (q0 >> 6)) * (KV)) * 2 + (KOFFB) + (q0 & 63);            \
  const char* pb1 = (const char*)(BPTR) +                                     \
      ((size_t)(n0 + (q1 >> 6)) * (KV)) * 2 + (KOFFB) + (q1 & 63);            \
  int aoff[4], boff[4];                                                       \
  _Pragma("unroll") for (int i = 0; i < 4; ++i) {                             \
    int ra = wm + i * 16 + l16;                                               \
    int oa = ra * 64 + quad * 16;                                             \
    aoff[i] = oa ^ (((ra >> 1) & 3) << 4);                                    \
    int rb = wn + i * 16 + l16;                                               \
    int ob = rb * 64 + quad * 16;                                             \
    boff[i] = ob ^ (((rb >> 1) & 3) << 4);                                    \
  }                                                                           \
  f32x4 acc[4][4] = {};

// ---------------- GEMM1: H = gelu(Xsel @ w1 + b1), M=4096 N=4096 K=1024 ----
// grid 32x32 = 1024 blocks; LDS 64 KB -> 2 blocks/CU. NITER = 32.
__global__ __launch_bounds__(256) void gemm1_k(const bf16* __restrict__ A,
                                               const bf16* __restrict__ Bt,
                                               const float* __restrict__ bias,
                                               bf16* __restrict__ H) {
  __shared__ __align__(16) bf16 A0[4096], A1[4096], A2[4096], A3[4096];  // 8 KB each
  __shared__ __align__(16) bf16 B0[4096], B1[4096], B2[4096], B3[4096];
  const int orig = blockIdx.y * 32 + blockIdx.x;               // nwg=1024
  const int wgid = (orig & 7) * 128 + (orig >> 3);             // bijective XCD chunk
  const int m0 = (wgid >> 5) * 128, n0 = (wgid & 31) * 128;
  GSETUP(A, Bt, Dz, 0)
  STG(A0, B0, 0)
  STG(A1, B1, 1)
  STG(A2, B2, 2)
  BAR_VM8;  // tile 0 landed (oldest 4); tiles 1,2 in flight
  for (int tt = 0; tt < 7; ++tt) {   // bodies t = 0..27, all staging
    const int t0 = tt * 4;
    GBODY(A0, B0, A3, B3, t0 + 0, 1, 0)
    GBODY(A1, B1, A0, B0, t0 + 1, 1, 0)
    GBODY(A2, B2, A1, B1, t0 + 2, 1, 0)
    GBODY(A3, B3, A2, B2, t0 + 3, 1, 0)
  }
  GBODY(A0, B0, A3, B3, 28, 1, 0)   // stages tile 31 -> stage 3; waits tile 29
  GBODY(A1, B1, A0, B0, 29, 0, 1)   // vmcnt(4): tile 30 landed
  GBODY(A2, B2, A0, B0, 30, 0, 2)   // vmcnt(0): tile 31 landed
  GBODY(A3, B3, A0, B0, 31, 0, 3)   // no barrier
  // epilogue: bias + exact GELU -> bf16  (C/D: col=lane&15, row=quad*4+reg)
#pragma unroll
  for (int mi = 0; mi < 4; ++mi) {
    int mb = m0 + wm + mi * 16 + quad * 4;
#pragma unroll
    for (int ni = 0; ni < 4; ++ni) {
      int n = n0 + wn + ni * 16 + l16;
      float bn = bias[n];
#pragma unroll
      for (int r = 0; r < 4; ++r) {
        float z = acc[mi][ni][r] + bn;
        float g = 0.5f * z * (1.f + erff(z * 0.70710678118654752f));
        H[(size_t)(mb + r) * DFFz + n] = (bf16)g;
      }
    }
  }
}

// ---- GEMM2: out[b,sel[m],:] += (H @ w2 [+ b2]) * gate, split-K=2, atomic scatter ----
// M=4096 N=1024 Kchunk=2048 -> NITER=64; grid (8,32,2) = 512 blocks = 2/CU.
// out pre-zeroed by prep_k each launch; f32 atomicAdd is order-independent.
__global__ __launch_bounds__(256) void gemm2_k(const bf16* __restrict__ A,
                                               const bf16* __restrict__ Bt,
                                               const float* __restrict__ b2,
                                               const int* __restrict__ sel_idx,
                                               const float* __restrict__ gates,
                                               float* __restrict__ out) {
  __shared__ __align__(16) bf16 A0[4096], A1[4096], A2[4096], A3[4096];
  __shared__ __align__(16) bf16 B0[4096], B1[4096], B2[4096], B3[4096];
  const int orig = blockIdx.y * 8 + blockIdx.x;                // nwg=256 per z
  const int wgid = (orig & 7) * 32 + (orig >> 3);              // bijective XCD chunk
  const int m0 = (wgid >> 3) * 128, n0 = (wgid & 7) * 128;
  GSETUP(A, Bt, DFFz, (size_t)blockIdx.z * 2048 * 2)
  STG(A0, B0, 0)
  STG(A1, B1, 1)
  STG(A2, B2, 2)
  BAR_VM8;
  for (int tt = 0; tt < 15; ++tt) {   // bodies t = 0..59, all staging
    const int t0 = tt * 4;
    GBODY(A0, B0, A3, B3, t0 + 0, 1, 0)
    GBODY(A1, B1, A0, B0, t0 + 1, 1, 0)
    GBODY(A2, B2, A1, B1, t0 + 2, 1, 0)
    GBODY(A3, B3, A2, B2, t0 + 3, 1, 0)
  }
  GBODY(A0, B0, A3, B3, 60, 1, 0)   // stages tile 63 -> stage 3; waits tile 61
  GBODY(A1, B1, A0, B0, 61, 0, 1)   // vmcnt(4): tile 62 landed
  GBODY(A2, B2, A0, B0, 62, 0, 2)   // vmcnt(0): tile 63 landed
  GBODY(A3, B3, A0, B0, 63, 0, 3)   // no barrier
  // fused epilogue: (+b2 on z==0), gate, atomic scatter into zeroed out
  const bool addb = (blockIdx.z == 0);
#pragma unroll
  for (int mi = 0; mi < 4; ++mi) {
#pragma unroll
    for (int r = 0; r < 4; ++r) {
      int m = m0 + wm + mi * 16 + quad * 4 + r;
      int b = m >> 10;
      int s = sel_idx[m];
      float g = gates[m];
      float* orow = out + ((size_t)b * Sz + s) * Dz;
#pragma unroll
      for (int ni = 0; ni < 4; ++ni) {
        int n = n0 + wn + ni * 16 + l16;
        float v = acc[mi][ni][r] + (addb ? b2[n] : 0.f);
        atomicAdd(&orow[n], v * g);
      }
    }
  }
}

extern "C" void kernel_launch(void* const* d_in, const int* in_sizes, int n_in,
                              void* d_out, int out_size, void* d_ws, size_t ws_size,
                              hipStream_t stream) {
  (void)in_sizes; (void)n_in; (void)out_size; (void)ws_size;
  const float* x  = (const float*)d_in[0];
  const float* rw = (const float*)d_in[1];
  const float* rb = (const float*)d_in[2];
  const float* w1 = (const float*)d_in[3];
  const float* b1 = (const float*)d_in[4];
  const float* w2 = (const float*)d_in[5];
  const float* b2 = (const float*)d_in[6];
  float* out = (float*)d_out;

  char* ws = (char*)d_ws;
  float* scores = (float*)ws;  ws += (size_t)Bz * Sz * 4;          // 64 KB
  int*   sel_idx = (int*)ws;   ws += (size_t)Bz * KACT * 4;        // 16 KB
  float* gates = (float*)ws;   ws += (size_t)Bz * KACT * 4;        // 16 KB
  bf16*  w2T = (bf16*)ws;      ws += (size_t)Dz * DFFz * 2;        // 8 MB  [1024][4096]
  bf16*  H = (bf16*)ws;        ws += (size_t)Bz * KACT * DFFz * 2; // 32 MB [4096][4096]
  bf16*  w1T = (bf16*)ws;      ws += (size_t)DFFz * Dz * 2;        // 8 MB  [4096][1024]
  bf16*  Xsel = (bf16*)ws;     ws += (size_t)Bz * KACT * Dz * 2;   // 8 MB  [4096][1024]

  prep_k<<<3 * 4096, 256, 0, stream>>>(x, rw, rb, scores, (float4*)out, w1, w1T, w2, w2T);
  select_gather_k<<<Bz * (Sz / 16), 256, 0, stream>>>(x, scores, sel_idx, gates, Xsel);
  gemm1_k<<<dim3(32, 32), 256, 0, stream>>>(Xsel, w1T, b1, H);
  gemm2_k<<<dim3(8, 32, 2), 256, 0, stream>>>(H, w2T, b2, sel_idx, gates, out);
}

// Round 6
// 296.292 us; speedup vs baseline: 1.1647x; 1.0264x over previous
//
#include <hip/hip_runtime.h>
#include <hip/hip_bf16.h>
#include <cstdint>
#include <cstddef>

// Problem constants (B=4, S=4096, D=1024, DFF=4096, K_ACT=1024)
#define Bz 4
#define Sz 4096
#define Dz 1024
#define DFFz 4096
#define KACT 1024

typedef __bf16 bf16;
typedef __attribute__((ext_vector_type(8))) __bf16 bf16x8;
typedef __attribute__((ext_vector_type(4))) __bf16 bf16x4;
typedef __attribute__((ext_vector_type(4))) float f32x4;

__device__ __forceinline__ void async16(const void* g, void* l) {
  __builtin_amdgcn_global_load_lds(
      (const __attribute__((address_space(1))) void*)g,
      (__attribute__((address_space(3))) void*)l, 16, 0, 0);
}

// ---- fused prep: [0,4096) router+zero | [4096,8192) w1 transpose | [8192,12288) w2 transpose ----
__global__ __launch_bounds__(256) void prep_k(const float* __restrict__ x,
                                              const float* __restrict__ rw,
                                              const float* __restrict__ rb,
                                              float* __restrict__ scores,
                                              float4* __restrict__ out4,
                                              const float* __restrict__ w1,
                                              bf16* __restrict__ w1T,
                                              const float* __restrict__ w2,
                                              bf16* __restrict__ w2T) {
  __shared__ float t[32][33];
  const int bid = blockIdx.x;
  const int tid = threadIdx.x;
  if (bid < 4096) {
    int row = bid * 4 + (tid >> 6);
    int lane = tid & 63;
    const float4* xr = (const float4*)(x + (size_t)row * Dz);
    const float4* wr = (const float4*)rw;
    float acc = 0.f;
#pragma unroll
    for (int i = 0; i < 4; ++i) {
      float4 a = xr[lane + i * 64];
      float4 w = wr[lane + i * 64];
      acc += a.x * w.x + a.y * w.y + a.z * w.z + a.w * w.w;
    }
#pragma unroll
    for (int d = 32; d; d >>= 1) acc += __shfl_down(acc, d, 64);
    if (lane == 0) scores[row] = acc + rb[0];
    float4* o = out4 + (size_t)bid * 4 * (Dz / 4);
    const float4 z = make_float4(0.f, 0.f, 0.f, 0.f);
#pragma unroll
    for (int i = 0; i < 4; ++i) o[tid + i * 256] = z;
  } else {
    const float* in; bf16* outp; int R, C, bx, by;
    if (bid < 8192) {
      in = w1; outp = w1T; R = Dz; C = DFFz;
      bx = (bid - 4096) & 127; by = (bid - 4096) >> 7;   // (128, 32)
    } else {
      in = w2; outp = w2T; R = DFFz; C = Dz;
      bx = (bid - 8192) & 31; by = (bid - 8192) >> 5;    // (32, 128)
    }
    int c0 = bx * 32, r0 = by * 32;
    int tx = tid & 31, ty = tid >> 5;  // (32, 8)
#pragma unroll
    for (int i = 0; i < 32; i += 8) t[ty + i][tx] = in[(size_t)(r0 + ty + i) * C + c0 + tx];
    __syncthreads();
#pragma unroll
    for (int i = 0; i < 32; i += 8)
      outp[(size_t)(c0 + ty + i) * R + r0 + tx] = (bf16)t[tx][ty + i];
  }
}

// ---- select top-K per batch, 16 tokens/block: scores staged in LDS once ----
__global__ __launch_bounds__(256) void select_gather_k(
    const float* __restrict__ x, const float* __restrict__ scores,
    int* __restrict__ sel_idx, float* __restrict__ gates, bf16* __restrict__ Xsel) {
  int b = blockIdx.x >> 8;            // 256 blocks per batch row
  int s0 = (blockIdx.x & 255) * 16;   // first of 16 tokens
  __shared__ float sc[Sz];
  __shared__ int red[16][4];
  __shared__ int rk[16];
  const int tid = threadIdx.x;
  const int wave = tid >> 6, lane = tid & 63;
  const float* srow = scores + (size_t)b * Sz;
#pragma unroll
  for (int i = 0; i < 4; ++i)
    ((float4*)sc)[tid + i * 256] = ((const float4*)srow)[tid + i * 256];
  __syncthreads();
  float mine[16];
#pragma unroll
  for (int j = 0; j < 16; ++j) mine[j] = sc[s0 + j];
  int cnt[16] = {};
  for (int t = tid; t < Sz; t += 256) {
    float o = sc[t];
#pragma unroll
    for (int j = 0; j < 16; ++j)
      cnt[j] += (o > mine[j]) || (o == mine[j] && t < s0 + j);
  }
#pragma unroll
  for (int j = 0; j < 16; ++j) {
    int c = cnt[j];
#pragma unroll
    for (int d = 32; d; d >>= 1) c += __shfl_down(c, d, 64);
    if (lane == 0) red[j][wave] = c;
  }
  __syncthreads();
  if (tid < 16) {
    int rank = red[tid][0] + red[tid][1] + red[tid][2] + red[tid][3];
    rk[tid] = rank;
    if (rank < KACT) {
      int m = b * KACT + rank;
      sel_idx[m] = s0 + tid;
      gates[m] = 1.f / (1.f + expf(-sc[s0 + tid]));
    }
  }
  __syncthreads();
#pragma unroll
  for (int j = 0; j < 16; ++j) {
    int rank = rk[j];
    if (rank >= KACT) continue;
    int m = b * KACT + rank;
    float4 v = ((const float4*)(x + ((size_t)b * Sz + s0 + j) * Dz))[tid];
    bf16x4 o = {(bf16)v.x, (bf16)v.y, (bf16)v.z, (bf16)v.w};
    ((bf16x4*)(Xsel + (size_t)m * Dz))[tid] = o;
  }
}

// ======== BK=64 2-phase GEMM (T3-minimum, m230-V0 pattern) ========
// R5 lesson (corrected cycle model): one mfma_16x16x32_bf16 occupies the SIMD
// matrix pipe ~19.4 cy (16x16 ubench 2075 TF = 844 FLOP/cy/SIMD), so the old
// BK=32 body had only ~310 cy/wave of MFMA per barrier interval vs a fixed
// ~1500-2000 cy stage/sync cost -> MfmaUtil pinned at ~19% no matter the
// pipeline depth (R4==R5 proved depth is not the lever). Fix: DOUBLE the MFMA
// work per barrier interval (BK=64 -> 32 MFMA/wave/body ~1240 cy/SIMD at 2
// resident blocks), stage-first so the DMA round-trip hides under it, one
// vmcnt(0)+lgkmcnt(0)+s_barrier per body (depth-2: counted vmcnt impossible,
// and R4/R5 showed it buys nothing anyway).
// Distinct LDS arrays + fully unrolled even/odd bodies (R4's proven fix for
// SIInsertWaitcnts' conservative vmcnt(0) on runtime-indexed LDS-DMA).
// Invariants: body t stages tile t+1 into S_{(t+1)&1}, reads S_{t&1}, then
// BAR_VM0 -> everyone's tile-(t+1) DMA landed AND everyone's reads of S_{t&1}
// done, so body t+1 may read S_{(t+1)&1} and overwrite S_{t&1}. Tail body has
// no stage and no barrier.
// LDS swizzle re-derived for 128 B rows (BK=64): involution
//   phys = off ^ (((off>>7)&7)<<4)
// 16B-slot index = (kc*4+quad) ^ (r&7) -> uniform across the wave ->
// conflict-free (R3/R5 measured 0 conflicts with the 64B-row analog).
// Stage side: linear LDS dest + pre-swizzled GLOBAL source (permutes 16B
// units within one 128B row -> coalescing preserved, same 128B segment).

#define BAR_VM0 asm volatile("s_waitcnt vmcnt(0) lgkmcnt(0)\n\ts_barrier" ::: "memory")

// stage tile T (k-offset T*64 elems = T*128 bytes); 8 loads, 32 KB total
#define STG(AS, BS, T)                                                        \
  {                                                                           \
    size_t ko_ = (size_t)(T) * 128;                                           \
    async16(pa0 + ko_, (char*)AS + Ld0);                                      \
    async16(pa1 + ko_, (char*)AS + Ld1);                                      \
    async16(pa2 + ko_, (char*)AS + Ld2);                                      \
    async16(pa3 + ko_, (char*)AS + Ld3);                                      \
    async16(pb0 + ko_, (char*)BS + Ld0);                                      \
    async16(pb1 + ko_, (char*)BS + Ld1);                                      \
    async16(pb2 + ko_, (char*)BS + Ld2);                                      \
    async16(pb3 + ko_, (char*)BS + Ld3);                                      \
  }

// one body: stage tile T+1 into AST/BST, read 24 frags from ARD/BRD,
// 32 MFMA (2 k-chunks x 4x4), then barrier if DOBAR
#define GB(ARD, BRD, AST, BST, T, DOSTAGE, DOBAR)                             \
  {                                                                           \
    if (DOSTAGE) { STG(AST, BST, (T) + 1) }                                   \
    const char* a_ = (const char*)ARD;                                        \
    const char* b_ = (const char*)BRD;                                        \
    bf16x8 af[2][4], bfr[2][4];                                               \
    _Pragma("unroll") for (int kc = 0; kc < 2; ++kc)                          \
      _Pragma("unroll") for (int i = 0; i < 4; ++i) {                         \
        af[kc][i] = *(const bf16x8*)(a_ + aoff[kc][i]);                       \
        bfr[kc][i] = *(const bf16x8*)(b_ + boff[kc][i]);                      \
      }                                                                       \
    __builtin_amdgcn_s_setprio(1);                                            \
    _Pragma("unroll") for (int kc = 0; kc < 2; ++kc)                          \
      _Pragma("unroll") for (int mi = 0; mi < 4; ++mi)                        \
        _Pragma("unroll") for (int ni = 0; ni < 4; ++ni)                      \
          acc[mi][ni] = __builtin_amdgcn_mfma_f32_16x16x32_bf16(              \
              af[kc][mi], bfr[kc][ni], acc[mi][ni], 0, 0, 0);                 \
    __builtin_amdgcn_s_setprio(0);                                            \
    if (DOBAR) { BAR_VM0; }                                                   \
  }

// common setup: 128x128 tile, BK=64, 4 waves (2M x 2N), 128 B LDS rows.
// staging map: thread loads LDS bytes Ld_j = tid*16 + j*4096 (j=0..3) of each
// 32 KB stage; the data for linear dest off is logical byte q = swz(off).
#define GSETUP(APTR, BPTR, KV, KOFFB)                                         \
  const int tid = threadIdx.x;                                                \
  const int wave = tid >> 6, lane = tid & 63;                                 \
  const int quad = lane >> 4, l16 = lane & 15;                                \
  const int wm = (wave >> 1) * 64, wn = (wave & 1) * 64;                      \
  const int Ld0 = tid * 16, Ld1 = Ld0 + 4096, Ld2 = Ld0 + 8192,               \
            Ld3 = Ld0 + 12288;                                                \
  const int q0 = Ld0 ^ (((Ld0 >> 7) & 7) << 4);                               \
  const int q1 = Ld1 ^ (((Ld1 >> 7) & 7) << 4);                               \
  const int q2 = Ld2 ^ (((Ld2 >> 7) & 7) << 4);                               \
  const int q3 = Ld3 ^ (((Ld3 >> 7) & 7) << 4);                               \
  const char* pa0 = (const char*)(APTR) +                                     \
      ((size_t)(m0 + (q0 >> 7)) * (KV)) * 2 + (KOFFB) + (q0 & 127);           \
  const char* pa1 = (const char*)(APTR) +                                     \
      ((size_t)(m0 + (q1 >> 7)) * (KV)) * 2 + (KOFFB) + (q1 & 127);           \
  const char* pa2 = (const char*)(APTR) +                                     \
      ((size_t)(m0 + (q2 >> 7)) * (KV)) * 2 + (KOFFB) + (q2 & 127);           \
  const char* pa3 = (const char*)(APTR) +                                     \
      ((size_t)(m0 + (q3 >> 7)) * (KV)) * 2 + (KOFFB) + (q3 & 127);           \
  const char* pb0 = (const char*)(BPTR) +                                     \
      ((size_t)(n0 + (q0 >> 7)) * (KV)) * 2 + (KOFFB) + (q0 & 127);           \
  const char* pb1 = (const char*)(BPTR) +                                     \
      ((size_t)(n0 + (q1 >> 7)) * (KV)) * 2 + (KOFFB) + (q1 & 127);           \
  const char* pb2 = (const char*)(BPTR) +                                     \
      ((size_t)(n0 + (q2 >> 7)) * (KV)) * 2 + (KOFFB) + (q2 & 127);           \
  const char* pb3 = (const char*)(BPTR) +                                     \
      ((size_t)(n0 + (q3 >> 7)) * (KV)) * 2 + (KOFFB) + (q3 & 127);           \
  int aoff[2][4], boff[2][4];                                                 \
  _Pragma("unroll") for (int kc = 0; kc < 2; ++kc)                            \
    _Pragma("unroll") for (int i = 0; i < 4; ++i) {                           \
      int ra = wm + i * 16 + l16;                                             \
      int oa = ra * 128 + kc * 64 + quad * 16;                                \
      aoff[kc][i] = oa ^ ((ra & 7) << 4);                                     \
      int rb = wn + i * 16 + l16;                                             \
      int ob = rb * 128 + kc * 64 + quad * 16;                                \
      boff[kc][i] = ob ^ ((rb & 7) << 4);                                     \
    }                                                                         \
  f32x4 acc[4][4] = {};

// ---------------- GEMM1: H = gelu(Xsel @ w1 + b1), M=4096 N=4096 K=1024 ----
// BK=64 -> NITER=16. grid 32x32 = 1024 blocks; LDS 64 KB -> 2 blocks/CU.
__global__ __launch_bounds__(256) void gemm1_k(const bf16* __restrict__ A,
                                               const bf16* __restrict__ Bt,
                                               const float* __restrict__ bias,
                                               bf16* __restrict__ H) {
  __shared__ __align__(16) bf16 A0[8192], A1[8192];  // 16 KB each
  __shared__ __align__(16) bf16 B0[8192], B1[8192];
  const int orig = blockIdx.y * 32 + blockIdx.x;               // nwg=1024
  const int wgid = (orig & 7) * 128 + (orig >> 3);             // bijective XCD chunk
  const int m0 = (wgid >> 5) * 128, n0 = (wgid & 31) * 128;
  GSETUP(A, Bt, Dz, 0)
  STG(A0, B0, 0)
  BAR_VM0;  // tile 0 landed everywhere
  for (int tt = 0; tt < 7; ++tt) {   // bodies t = 0..13
    GB(A0, B0, A1, B1, 2 * tt + 0, 1, 1)
    GB(A1, B1, A0, B0, 2 * tt + 1, 1, 1)
  }
  GB(A0, B0, A1, B1, 14, 1, 1)   // stages tile 15 -> S1
  GB(A1, B1, A0, B0, 15, 0, 0)   // final: no stage, no barrier
  // epilogue: bias + exact GELU -> bf16  (C/D: col=lane&15, row=quad*4+reg)
#pragma unroll
  for (int mi = 0; mi < 4; ++mi) {
    int mb = m0 + wm + mi * 16 + quad * 4;
#pragma unroll
    for (int ni = 0; ni < 4; ++ni) {
      int n = n0 + wn + ni * 16 + l16;
      float bn = bias[n];
#pragma unroll
      for (int r = 0; r < 4; ++r) {
        float z = acc[mi][ni][r] + bn;
        float g = 0.5f * z * (1.f + erff(z * 0.70710678118654752f));
        H[(size_t)(mb + r) * DFFz + n] = (bf16)g;
      }
    }
  }
}

// ---- GEMM2: out[b,sel[m],:] += (H @ w2 [+ b2]) * gate, split-K=2, atomic scatter ----
// M=4096 N=1024 Kchunk=2048 -> NITER=32; grid (8,32,2) = 512 blocks = 2/CU
// (exactly the LDS residency limit). out pre-zeroed by prep_k; f32 atomicAdd
// is order-independent.
__global__ __launch_bounds__(256) void gemm2_k(const bf16* __restrict__ A,
                                               const bf16* __restrict__ Bt,
                                               const float* __restrict__ b2,
                                               const int* __restrict__ sel_idx,
                                               const float* __restrict__ gates,
                                               float* __restrict__ out) {
  __shared__ __align__(16) bf16 A0[8192], A1[8192];
  __shared__ __align__(16) bf16 B0[8192], B1[8192];
  const int orig = blockIdx.y * 8 + blockIdx.x;                // nwg=256 per z
  const int wgid = (orig & 7) * 32 + (orig >> 3);              // bijective XCD chunk
  const int m0 = (wgid >> 3) * 128, n0 = (wgid & 7) * 128;
  GSETUP(A, Bt, DFFz, (size_t)blockIdx.z * 2048 * 2)
  STG(A0, B0, 0)
  BAR_VM0;
  for (int tt = 0; tt < 15; ++tt) {  // bodies t = 0..29
    GB(A0, B0, A1, B1, 2 * tt + 0, 1, 1)
    GB(A1, B1, A0, B0, 2 * tt + 1, 1, 1)
  }
  GB(A0, B0, A1, B1, 30, 1, 1)   // stages tile 31 -> S1
  GB(A1, B1, A0, B0, 31, 0, 0)   // final: no stage, no barrier
  // fused epilogue: (+b2 on z==0), gate, atomic scatter into zeroed out
  const bool addb = (blockIdx.z == 0);
#pragma unroll
  for (int mi = 0; mi < 4; ++mi) {
#pragma unroll
    for (int r = 0; r < 4; ++r) {
      int m = m0 + wm + mi * 16 + quad * 4 + r;
      int b = m >> 10;
      int s = sel_idx[m];
      float g = gates[m];
      float* orow = out + ((size_t)b * Sz + s) * Dz;
#pragma unroll
      for (int ni = 0; ni < 4; ++ni) {
        int n = n0 + wn + ni * 16 + l16;
        float v = acc[mi][ni][r] + (addb ? b2[n] : 0.f);
        atomicAdd(&orow[n], v * g);
      }
    }
  }
}

extern "C" void kernel_launch(void* const* d_in, const int* in_sizes, int n_in,
                              void* d_out, int out_size, void* d_ws, size_t ws_size,
                              hipStream_t stream) {
  (void)in_sizes; (void)n_in; (void)out_size; (void)ws_size;
  const float* x  = (const float*)d_in[0];
  const float* rw = (const float*)d_in[1];
  const float* rb = (const float*)d_in[2];
  const float* w1 = (const float*)d_in[3];
  const float* b1 = (const float*)d_in[4];
  const float* w2 = (const float*)d_in[5];
  const float* b2 = (const float*)d_in[6];
  float* out = (float*)d_out;

  char* ws = (char*)d_ws;
  float* scores = (float*)ws;  ws += (size_t)Bz * Sz * 4;          // 64 KB
  int*   sel_idx = (int*)ws;   ws += (size_t)Bz * KACT * 4;        // 16 KB
  float* gates = (float*)ws;   ws += (size_t)Bz * KACT * 4;        // 16 KB
  bf16*  w2T = (bf16*)ws;      ws += (size_t)Dz * DFFz * 2;        // 8 MB  [1024][4096]
  bf16*  H = (bf16*)ws;        ws += (size_t)Bz * KACT * DFFz * 2; // 32 MB [4096][4096]
  bf16*  w1T = (bf16*)ws;      ws += (size_t)DFFz * Dz * 2;        // 8 MB  [4096][1024]
  bf16*  Xsel = (bf16*)ws;     ws += (size_t)Bz * KACT * Dz * 2;   // 8 MB  [4096][1024]

  prep_k<<<3 * 4096, 256, 0, stream>>>(x, rw, rb, scores, (float4*)out, w1, w1T, w2, w2T);
  select_gather_k<<<Bz * (Sz / 16), 256, 0, stream>>>(x, scores, sel_idx, gates, Xsel);
  gemm1_k<<<dim3(32, 32), 256, 0, stream>>>(Xsel, w1T, b1, H);
  gemm2_k<<<dim3(8, 32, 2), 256, 0, stream>>>(H, w2T, b2, sel_idx, gates, out);
}